// Round 2
// baseline (560.777 us; speedup 1.0000x reference)
//
#include <hip/hip_runtime.h>
#include <hip/hip_bf16.h>
#include <stdint.h>

typedef __attribute__((ext_vector_type(8))) short bf16x8;   // 8 bf16 = 4 VGPRs
typedef __attribute__((ext_vector_type(4))) float f32x4;

__device__ __forceinline__ unsigned short f2bf(float f) {
    unsigned u = __builtin_bit_cast(unsigned, f);
    u += 0x7FFF + ((u >> 16) & 1);        // RNE (finite inputs)
    return (unsigned short)(u >> 16);
}
__device__ __forceinline__ float bf2f(unsigned short h) {
    return __builtin_bit_cast(float, (unsigned)h << 16);
}
__device__ __forceinline__ void load_lds16(const void* g, void* l) {
    __builtin_amdgcn_global_load_lds(
        (const __attribute__((address_space(1))) void*)g,
        (__attribute__((address_space(3))) void*)l, 16, 0, 0);
}

// ---------------------------------------------------------------------------
// fp32 -> bf16 bulk convert. n divisible by 2048; one thread = 8 elems.
// ---------------------------------------------------------------------------
__global__ __launch_bounds__(256)
void cvt_kernel(const float* __restrict__ src, unsigned short* __restrict__ dst)
{
    const long i = ((long)blockIdx.x * 256 + threadIdx.x) * 8;
    const float4 a = *(const float4*)(src + i);
    const float4 b = *(const float4*)(src + i + 4);
    bf16x8 r;
    r[0] = (short)f2bf(a.x); r[1] = (short)f2bf(a.y);
    r[2] = (short)f2bf(a.z); r[3] = (short)f2bf(a.w);
    r[4] = (short)f2bf(b.x); r[5] = (short)f2bf(b.y);
    r[6] = (short)f2bf(b.z); r[7] = (short)f2bf(b.w);
    *(bf16x8*)(dst + i) = r;
}

// ---------------------------------------------------------------------------
// C[m,n] = sum_k A[m,k]*Bt[n,k], K=1024, bf16, K-contiguous.
// 256x256 tile, 8 waves (2M x 4N), per-wave 128x64, BK=64.
// LDS 128 KiB: [buf][A0,A1,B0,B1] regions of 16 KiB, stored FRAGMENT-LINEAR:
// region = 16 subtiles of 1 KiB; subtile (i*2+s) holds lane l=(qd*16+fr) ->
// elem [row=i*16+fr][k=s*32+qd*8 ..+8]. Staged via per-thread pre-permuted
// global source (global_load_lds dest linear: wave base + lane*16).
// Every frag ds_read_b128 = one contiguous 1 KiB wave read, base+imm offset.
// Schedule: 8 phases / 2 K-tiles. Fragment reads issued at END of the phase
// BEFORE their consumer (WAR on same arrays; compiler renames), so LDS
// delivery overlaps MFMA. Counted vmcnt(6) (3 half-tiles in flight) at
// P3/P7, sealed by the phase-end barrier before cross-slice reads.
// MODE 0: relu+0.125 on q,k; scatter bf16 q/k/v. MODE 1: +bias, fp32 out.
// ---------------------------------------------------------------------------
#define LD_A(p, i, s) (*(const bf16x8*)(Abase + (p) * 65536 + ((i) * 2 + (s)) * 1024))
#define LD_B(p, j, s) (*(const bf16x8*)(Bbase + (p) * 65536 + ((j) * 2 + (s)) * 1024))

#define LDA4(p, ib) do { \
    afr[0][0] = LD_A(p, (ib)+0, 0); afr[0][1] = LD_A(p, (ib)+0, 1); \
    afr[1][0] = LD_A(p, (ib)+1, 0); afr[1][1] = LD_A(p, (ib)+1, 1); \
    afr[2][0] = LD_A(p, (ib)+2, 0); afr[2][1] = LD_A(p, (ib)+2, 1); \
    afr[3][0] = LD_A(p, (ib)+3, 0); afr[3][1] = LD_A(p, (ib)+3, 1); \
} while (0)

#define LDB2(p, jb) do { \
    bfr[(jb)+0][0] = LD_B(p, (jb)+0, 0); bfr[(jb)+0][1] = LD_B(p, (jb)+0, 1); \
    bfr[(jb)+1][0] = LD_B(p, (jb)+1, 0); bfr[(jb)+1][1] = LD_B(p, (jb)+1, 1); \
} while (0)

#define STAGE_A(p, half, tile) do { \
    const unsigned short* s_ = Ag + (long)(half) * 131072 + (tile) * 64; \
    unsigned short* d_ = ldsw + ((p) * 4 + (half)) * 8192; \
    load_lds16(s_, d_); \
    load_lds16(s_ + 65536, d_ + 4096); \
} while (0)

#define STAGE_B(p, half, tile) do { \
    const unsigned short* s_ = Bg + (long)(half) * 131072 + (tile) * 64; \
    unsigned short* d_ = ldsw + ((p) * 4 + 2 + (half)) * 8192; \
    load_lds16(s_, d_); \
    load_lds16(s_ + 65536, d_ + 4096); \
} while (0)

#define MM(ib, jb) do { \
    _Pragma("unroll") \
    for (int i_ = 0; i_ < 4; ++i_) { \
        acc[(ib)+i_][(jb)+0] = __builtin_amdgcn_mfma_f32_16x16x32_bf16(afr[i_][0], bfr[(jb)+0][0], acc[(ib)+i_][(jb)+0], 0, 0, 0); \
        acc[(ib)+i_][(jb)+1] = __builtin_amdgcn_mfma_f32_16x16x32_bf16(afr[i_][0], bfr[(jb)+1][0], acc[(ib)+i_][(jb)+1], 0, 0, 0); \
    } \
    _Pragma("unroll") \
    for (int i_ = 0; i_ < 4; ++i_) { \
        acc[(ib)+i_][(jb)+0] = __builtin_amdgcn_mfma_f32_16x16x32_bf16(afr[i_][1], bfr[(jb)+0][1], acc[(ib)+i_][(jb)+0], 0, 0, 0); \
        acc[(ib)+i_][(jb)+1] = __builtin_amdgcn_mfma_f32_16x16x32_bf16(afr[i_][1], bfr[(jb)+1][1], acc[(ib)+i_][(jb)+1], 0, 0, 0); \
    } \
} while (0)

// mid-phase: barrier then MFMA (lgkm waits are compiler-inserted, counted)
#define MID() do { \
    __builtin_amdgcn_sched_barrier(0); \
    __builtin_amdgcn_s_barrier(); \
    __builtin_amdgcn_sched_barrier(0); \
    __builtin_amdgcn_s_setprio(1); \
} while (0)
#define SP0() __builtin_amdgcn_s_setprio(0)
#define BARR() do { \
    __builtin_amdgcn_sched_barrier(0); \
    __builtin_amdgcn_s_barrier(); \
} while (0)
#define VM(n) asm volatile("s_waitcnt vmcnt(" #n ")" ::: "memory")

template<int MODE>
__global__ __launch_bounds__(512, 2)
void gemm_bt_kernel(const unsigned short* __restrict__ A,
                    const unsigned short* __restrict__ Bt,
                    __hip_bfloat16* __restrict__ o0,
                    __hip_bfloat16* __restrict__ o1,
                    __hip_bfloat16* __restrict__ o2,
                    float* __restrict__ outf,
                    const float* __restrict__ bias)
{
    constexpr int K  = 1024;
    constexpr int NT = (MODE == 0) ? 12 : 4;
    __shared__ __attribute__((aligned(16))) unsigned short lds[2][4][8192]; // 128 KiB

    // group-major swizzle: 8 m-tiles share B-tiles among co-resident blocks
    const int bid   = blockIdx.x;
    const int npg   = 8 * NT;
    const int group = bid / npg;
    const int rem   = bid - group * npg;
    const int gm    = (98 - group * 8 < 8) ? (98 - group * 8) : 8;
    const int mt    = group * 8 + rem % gm;
    const int nt    = rem / gm;
    const long m0 = (long)mt * 256;
    const long n0 = (long)nt * 256;

    const int t    = threadIdx.x;
    const int lane = t & 63;
    const int wv   = t >> 6;
    const int wr   = wv >> 2;        // 0..1 (M half)
    const int wc   = wv & 3;         // 0..3 (N quarter)
    const int fr   = lane & 15;
    const int qd   = lane >> 4;
    const int bh_  = wc >> 1;        // B half index

    // fragment-linear read bases (all reads = base + compile-time offset)
    const char* Abase = (const char*)&lds[0][wr][0] + lane * 16;
    const char* Bbase = (const char*)&lds[0][2 + bh_][0] + (wc & 1) * 8192 + lane * 16;

    // staging: thread t sources the element that frag-linear chunk t holds:
    // row = (t>>7)*16 + (t&15), k = ((t>>6)&1)*32 + ((t>>4)&3)*8; issue 2 = +64 rows.
    const int srow = ((t >> 7) << 4) + (t & 15);
    const int kcol = ((t >> 6) & 1) * 32 + ((t >> 4) & 3) * 8;
    const unsigned short* Ag = A  + (m0 + srow) * K + kcol;
    const unsigned short* Bg = Bt + (n0 + srow) * K + kcol;
    unsigned short* const ldsw = &lds[0][0][0] + wv * 512;   // wave slice (ushorts)

    f32x4 acc[8][4] = {};
    bf16x8 afr[4][2], bfr[4][2];

    // prologue: buf0 = tile0 (B,A), buf1-B/A = tile1; wait own 8, seal, read t0 frags
    STAGE_B(0, 0, 0); STAGE_B(0, 1, 0); STAGE_A(0, 0, 0); STAGE_A(0, 1, 0);
    STAGE_B(1, 0, 1); STAGE_B(1, 1, 1); STAGE_A(1, 0, 1); STAGE_A(1, 1, 1);
    VM(8);
    BARR();
    LDB2(0, 0); LDA4(0, 0); LDB2(0, 2);

#pragma unroll 1
    for (int it = 0; it < 7; ++it) {
        const int t2 = 2 * it + 2, t3 = 2 * it + 3;
        // ---- K-tile 2it (buf0) ----
        STAGE_B(0, 0, t2); MID(); MM(0, 0); SP0(); BARR();                      // P1
        STAGE_B(0, 1, t2); MID(); MM(0, 2); SP0(); LDA4(0, 4); BARR();          // P2
        STAGE_A(0, 0, t2); MID(); MM(4, 0); SP0(); VM(6); BARR();               // P3
        STAGE_A(0, 1, t2); MID(); MM(4, 2); SP0();
        LDB2(1, 0); LDA4(1, 0); LDB2(1, 2); BARR();                             // P4
        // ---- K-tile 2it+1 (buf1) ----
        STAGE_B(1, 0, t3); MID(); MM(0, 0); SP0(); BARR();                      // P5
        STAGE_B(1, 1, t3); MID(); MM(0, 2); SP0(); LDA4(1, 4); BARR();          // P6
        STAGE_A(1, 0, t3); MID(); MM(4, 0); SP0(); VM(6); BARR();               // P7
        STAGE_A(1, 1, t3); MID(); MM(4, 2); SP0();
        LDB2(0, 0); LDA4(0, 0); LDB2(0, 2); BARR();                             // P8
    }
    // ---- epilogue: tiles 14 (buf0), 15 (buf1); no new stages ----
    __builtin_amdgcn_s_setprio(1); MM(0, 0); SP0(); BARR();
    __builtin_amdgcn_s_setprio(1); MM(0, 2); SP0(); LDA4(0, 4); BARR();
    __builtin_amdgcn_s_setprio(1); MM(4, 0); SP0(); VM(0); BARR();
    __builtin_amdgcn_s_setprio(1); MM(4, 2); SP0();
    LDB2(1, 0); LDA4(1, 0); LDB2(1, 2); BARR();
    __builtin_amdgcn_s_setprio(1); MM(0, 0); SP0(); BARR();
    __builtin_amdgcn_s_setprio(1); MM(0, 2); SP0(); LDA4(1, 4); BARR();
    __builtin_amdgcn_s_setprio(1); MM(4, 0); MM(4, 2); SP0();

    // C/D layout: col = fr, row = qd*4 + reg. Wave tile: rows wr*128+, cols wc*64+.
    if (MODE == 0) {
        const int which = nt >> 2;  // 0:q 1:k 2:v (each 1024 cols = 4 n-tiles)
        __hip_bfloat16* dst = (which == 0) ? o0 : (which == 1) ? o1 : o2;
        const int colbase = ((nt & 3) << 8) + wc * 64;
        const bool act = (which < 2);
#pragma unroll
        for (int i = 0; i < 8; ++i) {
            const long mrow = m0 + wr * 128 + i * 16 + qd * 4;
#pragma unroll
            for (int r = 0; r < 4; ++r) {
                const long moff = (mrow + r) * 1024;
#pragma unroll
                for (int j = 0; j < 4; ++j) {
                    float v = acc[i][j][r];
                    if (act) v = fmaxf(v, 0.f) + 0.125f;
                    dst[moff + colbase + j * 16 + fr] = __float2bfloat16(v);
                }
            }
        }
    } else {
        const long nbase = n0 + wc * 64;
#pragma unroll
        for (int i = 0; i < 8; ++i) {
            const long mrow = m0 + wr * 128 + i * 16 + qd * 4;
#pragma unroll
            for (int r = 0; r < 4; ++r) {
                const long moff = (mrow + r) * 1024;
#pragma unroll
                for (int j = 0; j < 4; ++j)
                    outf[moff + nbase + j * 16 + fr] =
                        acc[i][j][r] + bias[nbase + j * 16 + fr];
            }
        }
    }
}

// ---------------------------------------------------------------------------
// Phase 2: kv[bh,e,d] partials over n, 14-way split (224 rows each).
// Block = (bb, h-octet, sp); 256 thr = 8 h-sub x (8 e-blk x 4 d-blk).
// Thread: 8e x 16d register tile -> FMA-bound (128 FMA per 6 ds_read_b128).
// kvp written in MFMA-B-FRAGMENT order: [sp][bh][(s2*4+j)*64+lane][jj],
// elem = kv[e = s2*32+(lane>>4)*8+jj][d = j*16+(lane&15)].
// ---------------------------------------------------------------------------
__global__ __launch_bounds__(256)
void kv_partial_kernel(const __hip_bfloat16* __restrict__ kbuf,
                       const __hip_bfloat16* __restrict__ vbuf,
                       float* __restrict__ kvp,    // [14][128][4096] frag-order
                       float* __restrict__ ksump)  // [14][128][64]
{
    __shared__ float kf[8][512];
    __shared__ float vf[8][512];
    const int t   = threadIdx.x;
    const int bid = blockIdx.x;
    const int sp   = bid % 14;
    const int hoct = (bid / 14) & 1;
    const int bb   = bid / 28;
    const long rowstart = (long)bb * 3136 + sp * 224;

    const int hsub = t >> 5;
    const int w    = t & 31;
    const int E    = w >> 2;         // e-block 0..7
    const int Dq   = w & 3;          // d-block 0..3
    const int cb   = hsub * 64;
    const int e0   = cb + E * 8;
    const int d0   = cb + Dq * 16;

    float kvacc[8][16];
#pragma unroll
    for (int i = 0; i < 8; ++i)
#pragma unroll
        for (int j = 0; j < 16; ++j) kvacc[i][j] = 0.f;
    float ksacc[8] = {0, 0, 0, 0, 0, 0, 0, 0};

    for (int it = 0; it < 28; ++it) {
        __syncthreads();
#pragma unroll
        for (int i = 0; i < 4; ++i) {
            const int idx = t + (i << 8);            // 0..1023
            const int rr  = (idx >> 6) & 7;
            const int c   = idx & 63;
            const long grow = rowstart + it * 8 + rr;
            const __hip_bfloat16* srcp =
                ((idx < 512) ? kbuf : vbuf) + grow * 1024 + hoct * 512 + c * 8;
            bf16x8 v8 = *(const bf16x8*)srcp;
            float* dstp = (idx < 512) ? &kf[rr][c * 8] : &vf[rr][c * 8];
#pragma unroll
            for (int jj = 0; jj < 8; ++jj)
                dstp[jj] = bf2f((unsigned short)v8[jj]);
        }
        __syncthreads();
#pragma unroll
        for (int r = 0; r < 8; ++r) {
            float ke[8], vd[16];
#pragma unroll
            for (int i = 0; i < 8; ++i)  ke[i] = kf[r][e0 + i];
#pragma unroll
            for (int j = 0; j < 16; ++j) vd[j] = vf[r][d0 + j];
#pragma unroll
            for (int i = 0; i < 8; ++i) {
                ksacc[i] += ke[i];
#pragma unroll
                for (int j = 0; j < 16; ++j)
                    kvacc[i][j] += ke[i] * vd[j];
            }
        }
    }

    const int bh = bb * 16 + hoct * 8 + hsub;
    const int s2 = E >> 2, qd = E & 3;
    float* outp = kvp + ((long)sp * 128 + bh) * 4096 + ((s2 * 4 + Dq) * 64 + qd * 16) * 8;
#pragma unroll
    for (int fr = 0; fr < 16; ++fr)
#pragma unroll
        for (int jj = 0; jj < 8; ++jj)
            outp[fr * 8 + jj] = kvacc[jj][fr];
    if (Dq == 0) {
#pragma unroll
        for (int i = 0; i < 8; ++i)
            ksump[sp * 8192 + bh * 64 + E * 8 + i] = ksacc[i];
    }
}

// ---------------------------------------------------------------------------
// Phase 2b: reduce 14 partials; kv -> bf16 frag-order, ksum -> fp32.
// ---------------------------------------------------------------------------
__global__ __launch_bounds__(256)
void reduce_kv_kernel(const float* __restrict__ kvp, const float* __restrict__ ksump,
                      unsigned short* __restrict__ kvb, float* __restrict__ ksum)
{
    const int idx = blockIdx.x * 256 + threadIdx.x;
    if (idx < 128 * 4096) {
        float a = 0.f;
#pragma unroll
        for (int s = 0; s < 14; ++s) a += kvp[(long)s * 128 * 4096 + idx];
        kvb[idx] = f2bf(a);
    } else {
        const int j = idx - 128 * 4096;
        if (j < 128 * 64) {
            float a = 0.f;
#pragma unroll
            for (int s = 0; s < 14; ++s) a += ksump[s * 8192 + j];
            ksum[j] = a;
        }
    }
}

// ---------------------------------------------------------------------------
// Phase 3: out2 = (q @ kv) * z via MFMA (K=64). Block = 64 rows x 64 d, one h.
// kv read as pre-packed B-fragments (one coalesced dwordx4 per frag).
// ---------------------------------------------------------------------------
__global__ __launch_bounds__(256)
void attn_out_kernel(const __hip_bfloat16* __restrict__ qbuf,
                     const unsigned short* __restrict__ kvb,  // [128][4096] frag-order
                     const float* __restrict__ ksum,          // [128][64]
                     __hip_bfloat16* __restrict__ out2)
{
    __shared__ __attribute__((aligned(16))) unsigned short qs[64][64];
    __shared__ float kss[64];
    __shared__ float zs[64];
    const int t   = threadIdx.x;
    const int bid = blockIdx.x;
    const int mc  = bid % 49;
    const int h   = (bid / 49) & 15;
    const int bb  = bid / 784;
    const long bh = bb * 16 + h;
    const long mbase = (long)bb * 3136 + mc * 64;

#pragma unroll
    for (int i = 0; i < 2; ++i) {
        const int idx = t + (i << 8);
        const int row = idx >> 3;
        const int c   = idx & 7;
        *(bf16x8*)&qs[row][c * 8] =
            *(const bf16x8*)(qbuf + (mbase + row) * 1024 + h * 64 + c * 8);
    }
    if (t < 64) kss[t] = ksum[bh * 64 + t];
    __syncthreads();
    if (t < 64) {
        float p = 0.f;
#pragma unroll
        for (int e = 0; e < 64; ++e) p += bf2f(qs[t][e]) * kss[e];
        zs[t] = 1.f / (p + 1e-6f);
    }
    __syncthreads();

    const int lane = t & 63;
    const int wv   = t >> 6;
    const int fr   = lane & 15;
    const int qd   = lane >> 4;

    bf16x8 bfv[2][4];
#pragma unroll
    for (int s2 = 0; s2 < 2; ++s2)
#pragma unroll
        for (int j = 0; j < 4; ++j)
            bfv[s2][j] = *(const bf16x8*)(kvb + bh * 4096 + ((s2 * 4 + j) * 64 + lane) * 8);

    const bf16x8 af0 = *(const bf16x8*)&qs[wv * 16 + fr][qd * 8];
    const bf16x8 af1 = *(const bf16x8*)&qs[wv * 16 + fr][32 + qd * 8];

    float zr[4];
#pragma unroll
    for (int r = 0; r < 4; ++r) zr[r] = zs[wv * 16 + qd * 4 + r];

#pragma unroll
    for (int j = 0; j < 4; ++j) {
        f32x4 acc = {};
        acc = __builtin_amdgcn_mfma_f32_16x16x32_bf16(af0, bfv[0][j], acc, 0, 0, 0);
        acc = __builtin_amdgcn_mfma_f32_16x16x32_bf16(af1, bfv[1][j], acc, 0, 0, 0);
#pragma unroll
        for (int r = 0; r < 4; ++r) {
            const long m = mbase + wv * 16 + qd * 4 + r;
            out2[m * 1024 + h * 64 + j * 16 + fr] = __float2bfloat16(acc[r] * zr[r]);
        }
    }
}

// ---------------------------------------------------------------------------
extern "C" void kernel_launch(void* const* d_in, const int* in_sizes, int n_in,
                              void* d_out, int out_size, void* d_ws, size_t ws_size,
                              hipStream_t stream)
{
    const float* x      = (const float*)d_in[0];
    const float* w_qkv  = (const float*)d_in[1];
    const float* w_proj = (const float*)d_in[2];
    const float* b_proj = (const float*)d_in[3];
    float* out = (float*)d_out;

    const long M = 25088;  // 128*196
    char* ws = (char*)d_ws;
    size_t off = 0;
    auto alloc = [&](size_t bytes) {
        char* p = ws + off;
        off += (bytes + 255) & ~(size_t)255;
        return p;
    };
    // ws (~112 MB): xb region reused as kvp/ksump after QKV GEMM consumes xb.
    char* xb_region = alloc(M * 1024 * 2);                 // 51.4 MB
    unsigned short* xb     = (unsigned short*)xb_region;
    float*          kvp    = (float*)xb_region;            // alias: 14*128*4096*4 = 29.4 MB
    float*          ksump  = (float*)(xb_region + (size_t)14 * 128 * 4096 * 4);
    unsigned short* wqkvb  = (unsigned short*)alloc((size_t)3072 * 1024 * 2);
    unsigned short* wprojb = (unsigned short*)alloc((size_t)1024 * 1024 * 2);
    unsigned short* vbuf   = (unsigned short*)alloc(M * 1024 * 2);
    unsigned short* kvb    = (unsigned short*)alloc((size_t)128 * 4096 * 2);
    float*          ksumr  = (float*)alloc((size_t)128 * 64 * 4);
    // d_out (103 MB) hosts qbuf+kbuf (both dead before final GEMM writes it).
    __hip_bfloat16* qbuf = (__hip_bfloat16*)d_out;
    __hip_bfloat16* kbuf = qbuf + M * 1024;
    __hip_bfloat16* out2 = (__hip_bfloat16*)vbuf;  // v dead after phase 2

    // 0) bf16 conversions (element counts all divisible by 2048)
    cvt_kernel<<<12544, 256, 0, stream>>>(x, xb);
    cvt_kernel<<<1536, 256, 0, stream>>>(w_qkv, wqkvb);
    cvt_kernel<<<512, 256, 0, stream>>>(w_proj, wprojb);
    // 1) qkv GEMM (256^2, frag-linear LDS, pipelined 8-phase), relu+0.125, scatter q/k/v
    gemm_bt_kernel<0><<<98 * 12, 512, 0, stream>>>(
        xb, wqkvb, qbuf, kbuf, (__hip_bfloat16*)vbuf, nullptr, nullptr);
    // 2) kv/ksum partials (frag-ordered)
    kv_partial_kernel<<<224, 256, 0, stream>>>(kbuf, (const __hip_bfloat16*)vbuf, kvp, ksump);
    // 2b) reduce -> kvb bf16 + ksum fp32
    reduce_kv_kernel<<<2080, 256, 0, stream>>>(kvp, ksump, kvb, ksumr);
    // 3) out2 = (q @ kv) * z   (MFMA, K=64)
    attn_out_kernel<<<8 * 16 * 49, 256, 0, stream>>>(qbuf, kvb, ksumr, out2);
    // 4) out = out2 @ w_proj^T + bias
    gemm_bt_kernel<1><<<98 * 4, 512, 0, stream>>>(
        (const unsigned short*)out2, wprojb, nullptr, nullptr, nullptr, out, b_proj);
}

// Round 3
// 524.785 us; speedup vs baseline: 1.0686x; 1.0686x over previous
//
#include <hip/hip_runtime.h>
#include <hip/hip_bf16.h>
#include <stdint.h>

typedef __attribute__((ext_vector_type(8))) short bf16x8;   // 8 bf16 = 4 VGPRs
typedef __attribute__((ext_vector_type(4))) float f32x4;

__device__ __forceinline__ unsigned short f2bf(float f) {
    unsigned u = __builtin_bit_cast(unsigned, f);
    u += 0x7FFF + ((u >> 16) & 1);        // RNE (finite inputs)
    return (unsigned short)(u >> 16);
}
__device__ __forceinline__ float bf2f(unsigned short h) {
    return __builtin_bit_cast(float, (unsigned)h << 16);
}
__device__ __forceinline__ void load_lds16(const void* g, void* l) {
    __builtin_amdgcn_global_load_lds(
        (const __attribute__((address_space(1))) void*)g,
        (__attribute__((address_space(3))) void*)l, 16, 0, 0);
}

// ---------------------------------------------------------------------------
// fp32 -> bf16 bulk convert, all three tensors in ONE launch.
// Block ranges: [0,12544) x, [12544,14080) w_qkv, [14080,14592) w_proj.
// Each range's element count divisible by 2048; one thread = 8 elems.
// ---------------------------------------------------------------------------
__global__ __launch_bounds__(256)
void cvt_all_kernel(const float* __restrict__ x,      unsigned short* __restrict__ xb,
                    const float* __restrict__ wqkv,   unsigned short* __restrict__ wqkvb,
                    const float* __restrict__ wproj,  unsigned short* __restrict__ wprojb)
{
    const int bid = blockIdx.x;
    const float* src; unsigned short* dst; long base;
    if (bid < 12544)      { src = x;     dst = xb;     base = bid; }
    else if (bid < 14080) { src = wqkv;  dst = wqkvb;  base = bid - 12544; }
    else                  { src = wproj; dst = wprojb; base = bid - 14080; }
    const long i = (base * 256 + threadIdx.x) * 8;
    const float4 a = *(const float4*)(src + i);
    const float4 b = *(const float4*)(src + i + 4);
    bf16x8 r;
    r[0] = (short)f2bf(a.x); r[1] = (short)f2bf(a.y);
    r[2] = (short)f2bf(a.z); r[3] = (short)f2bf(a.w);
    r[4] = (short)f2bf(b.x); r[5] = (short)f2bf(b.y);
    r[6] = (short)f2bf(b.z); r[7] = (short)f2bf(b.w);
    *(bf16x8*)(dst + i) = r;
}

// ---------------------------------------------------------------------------
// C[m,n] = sum_k A[m,k]*Bt[n,k], K=1024, bf16 operands, K-contiguous.
// 128x128 tile, 4 waves, 64x64/wave, 4x4 x mfma 16x16x32. BK=64.
// Staging: global_load_lds width=16 (m97), XOR chunk-swizzle (chunk^=row&7)
// so frag ds_read_b128 is 2-way (free). Group-swizzled grid for L2 locality.
// MODE 0: epilogue relu+0.125 on q,k; scatter bf16 q/k/v. MODE 1: +bias, fp32.
// [R1/R2 post-mortem: 256^2 8-phase variants measured 166.4 / 203.9 us vs
//  this structure's 162.8 on this shape (K=16 tiles, 4.6 grid rounds) —
//  reverted to measured best.]
// ---------------------------------------------------------------------------
template<int MODE>
__global__ __launch_bounds__(256, 2)
void gemm_bt_kernel(const unsigned short* __restrict__ A,
                    const unsigned short* __restrict__ Bt,
                    __hip_bfloat16* __restrict__ o0,
                    __hip_bfloat16* __restrict__ o1,
                    __hip_bfloat16* __restrict__ o2,
                    float* __restrict__ outf,
                    const float* __restrict__ bias)
{
    constexpr int K  = 1024;
    constexpr int NT = (MODE == 0) ? 24 : 8;
    __shared__ __attribute__((aligned(16))) unsigned short As[128 * 64];
    __shared__ __attribute__((aligned(16))) unsigned short Bs[128 * 64];

    // group-major swizzle: 8 m-tiles share B-tiles among co-resident blocks
    const int bid   = blockIdx.x;
    const int npg   = 8 * NT;
    const int group = bid / npg;
    const int rem   = bid - group * npg;
    const int gm    = (196 - group * 8 < 8) ? (196 - group * 8) : 8;
    const int mt    = group * 8 + rem % gm;
    const int nt    = rem / gm;
    const long m0 = (long)mt * 128;
    const long n0 = (long)nt * 128;

    const int t    = threadIdx.x;
    const int lane = t & 63;
    const int wv   = t >> 6;
    const int wm   = (wv & 1) << 6;
    const int wn   = (wv >> 1) << 6;
    const int fr   = lane & 15;
    const int qd   = lane >> 4;

    f32x4 acc[4][4] = {};

    // staging: thread t -> LDS row c*32 + (t>>3), LDS chunk t&7, which holds
    // global chunk (t&7)^(row&7). LDS dest = uniform base + lane*16.
    const int srow   = t >> 3;                  // 0..31
    const int gch    = (t & 7) ^ (srow & 7);
    const int wbytes = (t & 192) << 4;          // wave id * 1024

    const unsigned short* Ag = A  + (m0 + srow) * K + gch * 8;
    const unsigned short* Bg = Bt + (n0 + srow) * K + gch * 8;

    for (int kb = 0; kb < K; kb += 64) {
        __syncthreads();
#pragma unroll
        for (int c = 0; c < 4; ++c) {
            load_lds16(Ag + (long)c * 32 * K + kb, (char*)As + c * 4096 + wbytes);
            load_lds16(Bg + (long)c * 32 * K + kb, (char*)Bs + c * 4096 + wbytes);
        }
        __syncthreads();   // compiler emits s_waitcnt vmcnt(0) before barrier
#pragma unroll
        for (int s = 0; s < 2; ++s) {
            bf16x8 af[4], bfv[4];
            const int ch = ((s << 2) + qd) ^ (fr & 7);  // un-swizzle (row&7==fr&7)
#pragma unroll
            for (int i = 0; i < 4; ++i)
                af[i] = *(const bf16x8*)(As + (wm + i * 16 + fr) * 64 + ch * 8);
#pragma unroll
            for (int j = 0; j < 4; ++j)
                bfv[j] = *(const bf16x8*)(Bs + (wn + j * 16 + fr) * 64 + ch * 8);
#pragma unroll
            for (int i = 0; i < 4; ++i)
#pragma unroll
                for (int j = 0; j < 4; ++j)
                    acc[i][j] = __builtin_amdgcn_mfma_f32_16x16x32_bf16(
                        af[i], bfv[j], acc[i][j], 0, 0, 0);
        }
    }

    // C/D layout: col = fr, row = qd*4 + reg
    if (MODE == 0) {
        const int which = nt >> 3;  // 0:q 1:k 2:v
        __hip_bfloat16* dst = (which == 0) ? o0 : (which == 1) ? o1 : o2;
        const int colbase = ((nt & 7) << 7) + wn;
        const bool act = (which < 2);
#pragma unroll
        for (int i = 0; i < 4; ++i) {
            const long mrow = m0 + wm + i * 16 + qd * 4;
#pragma unroll
            for (int r = 0; r < 4; ++r) {
                const long moff = (mrow + r) * 1024;
#pragma unroll
                for (int j = 0; j < 4; ++j) {
                    float v = acc[i][j][r];
                    if (act) v = fmaxf(v, 0.f) + 0.125f;
                    dst[moff + colbase + j * 16 + fr] = __float2bfloat16(v);
                }
            }
        }
    } else {
        const long nbase = n0 + wn;
#pragma unroll
        for (int i = 0; i < 4; ++i) {
            const long mrow = m0 + wm + i * 16 + qd * 4;
#pragma unroll
            for (int r = 0; r < 4; ++r) {
                const long moff = (mrow + r) * 1024;
#pragma unroll
                for (int j = 0; j < 4; ++j)
                    outf[moff + nbase + j * 16 + fr] =
                        acc[i][j][r] + bias[nbase + j * 16 + fr];
            }
        }
    }
}

// ---------------------------------------------------------------------------
// Phase 2: kv[bh,e,d] partials over n, 14-way split (224 rows each).
// Block = (bb, h-octet, sp); 256 thr = 8 h-sub x (8 e-blk x 4 d-blk).
// Thread: 8e x 16d register tile -> FMA-bound (128 FMA per 6 ds_read_b128).
// kvp written in MFMA-B-FRAGMENT order: [sp][bh][(s2*4+j)*64+lane][jj],
// elem = kv[e = s2*32+(lane>>4)*8+jj][d = j*16+(lane&15)].
// ---------------------------------------------------------------------------
__global__ __launch_bounds__(256)
void kv_partial_kernel(const __hip_bfloat16* __restrict__ kbuf,
                       const __hip_bfloat16* __restrict__ vbuf,
                       float* __restrict__ kvp,    // [14][128][4096] frag-order
                       float* __restrict__ ksump)  // [14][128][64]
{
    __shared__ float kf[8][512];
    __shared__ float vf[8][512];
    const int t   = threadIdx.x;
    const int bid = blockIdx.x;
    const int sp   = bid % 14;
    const int hoct = (bid / 14) & 1;
    const int bb   = bid / 28;
    const long rowstart = (long)bb * 3136 + sp * 224;

    const int hsub = t >> 5;
    const int w    = t & 31;
    const int E    = w >> 2;         // e-block 0..7
    const int Dq   = w & 3;          // d-block 0..3
    const int cb   = hsub * 64;
    const int e0   = cb + E * 8;
    const int d0   = cb + Dq * 16;

    float kvacc[8][16];
#pragma unroll
    for (int i = 0; i < 8; ++i)
#pragma unroll
        for (int j = 0; j < 16; ++j) kvacc[i][j] = 0.f;
    float ksacc[8] = {0, 0, 0, 0, 0, 0, 0, 0};

    for (int it = 0; it < 28; ++it) {
        __syncthreads();
#pragma unroll
        for (int i = 0; i < 4; ++i) {
            const int idx = t + (i << 8);            // 0..1023
            const int rr  = (idx >> 6) & 7;
            const int c   = idx & 63;
            const long grow = rowstart + it * 8 + rr;
            const __hip_bfloat16* srcp =
                ((idx < 512) ? kbuf : vbuf) + grow * 1024 + hoct * 512 + c * 8;
            bf16x8 v8 = *(const bf16x8*)srcp;
            float* dstp = (idx < 512) ? &kf[rr][c * 8] : &vf[rr][c * 8];
#pragma unroll
            for (int jj = 0; jj < 8; ++jj)
                dstp[jj] = bf2f((unsigned short)v8[jj]);
        }
        __syncthreads();
#pragma unroll
        for (int r = 0; r < 8; ++r) {
            float ke[8], vd[16];
#pragma unroll
            for (int i = 0; i < 8; ++i)  ke[i] = kf[r][e0 + i];
#pragma unroll
            for (int j = 0; j < 16; ++j) vd[j] = vf[r][d0 + j];
#pragma unroll
            for (int i = 0; i < 8; ++i) {
                ksacc[i] += ke[i];
#pragma unroll
                for (int j = 0; j < 16; ++j)
                    kvacc[i][j] += ke[i] * vd[j];
            }
        }
    }

    const int bh = bb * 16 + hoct * 8 + hsub;
    const int s2 = E >> 2, qd = E & 3;
    float* outp = kvp + ((long)sp * 128 + bh) * 4096 + ((s2 * 4 + Dq) * 64 + qd * 16) * 8;
#pragma unroll
    for (int fr = 0; fr < 16; ++fr)
#pragma unroll
        for (int jj = 0; jj < 8; ++jj)
            outp[fr * 8 + jj] = kvacc[jj][fr];
    if (Dq == 0) {
#pragma unroll
        for (int i = 0; i < 8; ++i)
            ksump[sp * 8192 + bh * 64 + E * 8 + i] = ksacc[i];
    }
}

// ---------------------------------------------------------------------------
// Phase 2b: reduce 14 partials; kv -> bf16 frag-order, ksum -> fp32.
// ---------------------------------------------------------------------------
__global__ __launch_bounds__(256)
void reduce_kv_kernel(const float* __restrict__ kvp, const float* __restrict__ ksump,
                      unsigned short* __restrict__ kvb, float* __restrict__ ksum)
{
    const int idx = blockIdx.x * 256 + threadIdx.x;
    if (idx < 128 * 4096) {
        float a = 0.f;
#pragma unroll
        for (int s = 0; s < 14; ++s) a += kvp[(long)s * 128 * 4096 + idx];
        kvb[idx] = f2bf(a);
    } else {
        const int j = idx - 128 * 4096;
        if (j < 128 * 64) {
            float a = 0.f;
#pragma unroll
            for (int s = 0; s < 14; ++s) a += ksump[s * 8192 + j];
            ksum[j] = a;
        }
    }
}

// ---------------------------------------------------------------------------
// Phase 3: out2 = (q @ kv) * z via MFMA (K=64). Block = 64 rows x 64 d, one h.
// kv read as pre-packed B-fragments (one coalesced dwordx4 per frag).
// qs padded to 72 (144 B row stride, 16B-aligned): kills the single-bank-group
// serialization of stride-128B row reads (frag loads + z dot).
// z computed by all 4 waves (16-elem partials, per-lane rotated to avoid
// bank conflicts) instead of one wave's serial 64-iter loop.
// ---------------------------------------------------------------------------
__global__ __launch_bounds__(256)
void attn_out_kernel(const __hip_bfloat16* __restrict__ qbuf,
                     const unsigned short* __restrict__ kvb,  // [128][4096] frag-order
                     const float* __restrict__ ksum,          // [128][64]
                     __hip_bfloat16* __restrict__ out2)
{
    __shared__ __attribute__((aligned(16))) unsigned short qs[64][72];
    __shared__ float kss[64];
    __shared__ float zpart[4][64];
    __shared__ float zs[64];
    const int t   = threadIdx.x;
    const int bid = blockIdx.x;
    const int mc  = bid % 49;
    const int h   = (bid / 49) & 15;
    const int bb  = bid / 784;
    const long bh = bb * 16 + h;
    const long mbase = (long)bb * 3136 + mc * 64;

#pragma unroll
    for (int i = 0; i < 2; ++i) {
        const int idx = t + (i << 8);
        const int row = idx >> 3;
        const int c   = idx & 7;
        *(bf16x8*)&qs[row][c * 8] =
            *(const bf16x8*)(qbuf + (mbase + row) * 1024 + h * 64 + c * 8);
    }
    if (t < 64) kss[t] = ksum[bh * 64 + t];
    __syncthreads();
    {   // z partial dot: wave w covers e in [w*16, w*16+16), rotated per lane
        const int zr_ = t & 63, zp_ = t >> 6;
#pragma unroll
        for (int ee = 0; ee < 1; ++ee) {}  // (keep structure simple)
        float p = 0.f;
#pragma unroll
        for (int ee = 0; ee < 16; ++ee) {
            const int e = zp_ * 16 + ((ee + zr_) & 15);
            p += bf2f(qs[zr_][e]) * kss[e];
        }
        zpart[zp_][zr_] = p;
    }
    __syncthreads();
    if (t < 64)
        zs[t] = 1.f / (zpart[0][t] + zpart[1][t] + zpart[2][t] + zpart[3][t] + 1e-6f);
    __syncthreads();

    const int lane = t & 63;
    const int wv   = t >> 6;
    const int fr   = lane & 15;
    const int qd   = lane >> 4;

    bf16x8 bfv[2][4];
#pragma unroll
    for (int s2 = 0; s2 < 2; ++s2)
#pragma unroll
        for (int j = 0; j < 4; ++j)
            bfv[s2][j] = *(const bf16x8*)(kvb + bh * 4096 + ((s2 * 4 + j) * 64 + lane) * 8);

    const bf16x8 af0 = *(const bf16x8*)&qs[wv * 16 + fr][qd * 8];
    const bf16x8 af1 = *(const bf16x8*)&qs[wv * 16 + fr][32 + qd * 8];

    float zr[4];
#pragma unroll
    for (int r = 0; r < 4; ++r) zr[r] = zs[wv * 16 + qd * 4 + r];

#pragma unroll
    for (int j = 0; j < 4; ++j) {
        f32x4 acc = {};
        acc = __builtin_amdgcn_mfma_f32_16x16x32_bf16(af0, bfv[0][j], acc, 0, 0, 0);
        acc = __builtin_amdgcn_mfma_f32_16x16x32_bf16(af1, bfv[1][j], acc, 0, 0, 0);
#pragma unroll
        for (int r = 0; r < 4; ++r) {
            const long m = mbase + wv * 16 + qd * 4 + r;
            out2[m * 1024 + h * 64 + j * 16 + fr] = __float2bfloat16(acc[r] * zr[r]);
        }
    }
}

// ---------------------------------------------------------------------------
extern "C" void kernel_launch(void* const* d_in, const int* in_sizes, int n_in,
                              void* d_out, int out_size, void* d_ws, size_t ws_size,
                              hipStream_t stream)
{
    const float* x      = (const float*)d_in[0];
    const float* w_qkv  = (const float*)d_in[1];
    const float* w_proj = (const float*)d_in[2];
    const float* b_proj = (const float*)d_in[3];
    float* out = (float*)d_out;

    const long M = 25088;  // 128*196
    char* ws = (char*)d_ws;
    size_t off = 0;
    auto alloc = [&](size_t bytes) {
        char* p = ws + off;
        off += (bytes + 255) & ~(size_t)255;
        return p;
    };
    // ws (~112 MB): xb region reused as kvp/ksump after QKV GEMM consumes xb.
    char* xb_region = alloc(M * 1024 * 2);                 // 51.4 MB
    unsigned short* xb     = (unsigned short*)xb_region;
    float*          kvp    = (float*)xb_region;            // alias: 14*128*4096*4 = 29.4 MB
    float*          ksump  = (float*)(xb_region + (size_t)14 * 128 * 4096 * 4);
    unsigned short* wqkvb  = (unsigned short*)alloc((size_t)3072 * 1024 * 2);
    unsigned short* wprojb = (unsigned short*)alloc((size_t)1024 * 1024 * 2);
    unsigned short* vbuf   = (unsigned short*)alloc(M * 1024 * 2);
    unsigned short* kvb    = (unsigned short*)alloc((size_t)128 * 4096 * 2);
    float*          ksumr  = (float*)alloc((size_t)128 * 64 * 4);
    // d_out (103 MB) hosts qbuf+kbuf (both dead before final GEMM writes it).
    __hip_bfloat16* qbuf = (__hip_bfloat16*)d_out;
    __hip_bfloat16* kbuf = qbuf + M * 1024;
    __hip_bfloat16* out2 = (__hip_bfloat16*)vbuf;  // v dead after phase 2

    // 0) bf16 conversions, single launch (block ranges: 12544 x / 1536 / 512)
    cvt_all_kernel<<<14592, 256, 0, stream>>>(x, xb, w_qkv, wqkvb, w_proj, wprojb);
    // 1) qkv GEMM, fused relu+0.125, scatter q/k/v
    gemm_bt_kernel<0><<<196 * 24, 256, 0, stream>>>(
        xb, wqkvb, qbuf, kbuf, (__hip_bfloat16*)vbuf, nullptr, nullptr);
    // 2) kv/ksum partials (frag-ordered)
    kv_partial_kernel<<<224, 256, 0, stream>>>(kbuf, (const __hip_bfloat16*)vbuf, kvp, ksump);
    // 2b) reduce -> kvb bf16 + ksum fp32
    reduce_kv_kernel<<<2080, 256, 0, stream>>>(kvp, ksump, kvb, ksumr);
    // 3) out2 = (q @ kv) * z   (MFMA, K=64)
    attn_out_kernel<<<8 * 16 * 49, 256, 0, stream>>>(qbuf, kvb, ksumr, out2);
    // 4) out = out2 @ w_proj^T + bias
    gemm_bt_kernel<1><<<196 * 8, 256, 0, stream>>>(
        (const unsigned short*)out2, wprojb, nullptr, nullptr, nullptr, out, b_proj);
}

// Round 4
// 516.201 us; speedup vs baseline: 1.0864x; 1.0166x over previous
//
#include <hip/hip_runtime.h>
#include <hip/hip_bf16.h>
#include <stdint.h>

typedef __attribute__((ext_vector_type(8))) short bf16x8;   // 8 bf16 = 4 VGPRs
typedef __attribute__((ext_vector_type(4))) float f32x4;

__device__ __forceinline__ unsigned short f2bf(float f) {
    unsigned u = __builtin_bit_cast(unsigned, f);
    u += 0x7FFF + ((u >> 16) & 1);        // RNE (finite inputs)
    return (unsigned short)(u >> 16);
}
__device__ __forceinline__ float bf2f(unsigned short h) {
    return __builtin_bit_cast(float, (unsigned)h << 16);
}
__device__ __forceinline__ void load_lds16(const void* g, void* l) {
    __builtin_amdgcn_global_load_lds(
        (const __attribute__((address_space(1))) void*)g,
        (__attribute__((address_space(3))) void*)l, 16, 0, 0);
}

// ---------------------------------------------------------------------------
// fp32 -> bf16 bulk convert, all three tensors in ONE launch.
// Block ranges: [0,12544) x, [12544,14080) w_qkv, [14080,14592) w_proj.
// Each range's element count divisible by 2048; one thread = 8 elems.
// ---------------------------------------------------------------------------
__global__ __launch_bounds__(256)
void cvt_all_kernel(const float* __restrict__ x,      unsigned short* __restrict__ xb,
                    const float* __restrict__ wqkv,   unsigned short* __restrict__ wqkvb,
                    const float* __restrict__ wproj,  unsigned short* __restrict__ wprojb)
{
    const int bid = blockIdx.x;
    const float* src; unsigned short* dst; long base;
    if (bid < 12544)      { src = x;     dst = xb;     base = bid; }
    else if (bid < 14080) { src = wqkv;  dst = wqkvb;  base = bid - 12544; }
    else                  { src = wproj; dst = wprojb; base = bid - 14080; }
    const long i = (base * 256 + threadIdx.x) * 8;
    const float4 a = *(const float4*)(src + i);
    const float4 b = *(const float4*)(src + i + 4);
    bf16x8 r;
    r[0] = (short)f2bf(a.x); r[1] = (short)f2bf(a.y);
    r[2] = (short)f2bf(a.z); r[3] = (short)f2bf(a.w);
    r[4] = (short)f2bf(b.x); r[5] = (short)f2bf(b.y);
    r[6] = (short)f2bf(b.z); r[7] = (short)f2bf(b.w);
    *(bf16x8*)(dst + i) = r;
}

// ---------------------------------------------------------------------------
// C[m,n] = sum_k A[m,k]*Bt[n,k], K=1024, bf16 operands, K-contiguous.
// 128x128 tile, 4 waves, 64x64/wave, 4x4 x mfma 16x16x32. BK=64.
// Staging: global_load_lds width=16 (m97), XOR chunk-swizzle (chunk^=row&7)
// so frag ds_read_b128 is 2-way (free). Group-swizzled grid for L2 locality.
// MODE 0: epilogue relu+0.125 on q,k; scatter bf16 q/k/v. MODE 1: +bias, fp32.
// [R1/R2 post-mortem: 256^2 8-phase variants measured 166.4 / 203.9 us vs
//  this structure's 162.8 on this shape (K=16 tiles, 4.6 grid rounds) —
//  measured best; do not touch.]
// ---------------------------------------------------------------------------
template<int MODE>
__global__ __launch_bounds__(256, 2)
void gemm_bt_kernel(const unsigned short* __restrict__ A,
                    const unsigned short* __restrict__ Bt,
                    __hip_bfloat16* __restrict__ o0,
                    __hip_bfloat16* __restrict__ o1,
                    __hip_bfloat16* __restrict__ o2,
                    float* __restrict__ outf,
                    const float* __restrict__ bias)
{
    constexpr int K  = 1024;
    constexpr int NT = (MODE == 0) ? 24 : 8;
    __shared__ __attribute__((aligned(16))) unsigned short As[128 * 64];
    __shared__ __attribute__((aligned(16))) unsigned short Bs[128 * 64];

    // group-major swizzle: 8 m-tiles share B-tiles among co-resident blocks
    const int bid   = blockIdx.x;
    const int npg   = 8 * NT;
    const int group = bid / npg;
    const int rem   = bid - group * npg;
    const int gm    = (196 - group * 8 < 8) ? (196 - group * 8) : 8;
    const int mt    = group * 8 + rem % gm;
    const int nt    = rem / gm;
    const long m0 = (long)mt * 128;
    const long n0 = (long)nt * 128;

    const int t    = threadIdx.x;
    const int lane = t & 63;
    const int wv   = t >> 6;
    const int wm   = (wv & 1) << 6;
    const int wn   = (wv >> 1) << 6;
    const int fr   = lane & 15;
    const int qd   = lane >> 4;

    f32x4 acc[4][4] = {};

    // staging: thread t -> LDS row c*32 + (t>>3), LDS chunk t&7, which holds
    // global chunk (t&7)^(row&7). LDS dest = uniform base + lane*16.
    const int srow   = t >> 3;                  // 0..31
    const int gch    = (t & 7) ^ (srow & 7);
    const int wbytes = (t & 192) << 4;          // wave id * 1024

    const unsigned short* Ag = A  + (m0 + srow) * K + gch * 8;
    const unsigned short* Bg = Bt + (n0 + srow) * K + gch * 8;

    for (int kb = 0; kb < K; kb += 64) {
        __syncthreads();
#pragma unroll
        for (int c = 0; c < 4; ++c) {
            load_lds16(Ag + (long)c * 32 * K + kb, (char*)As + c * 4096 + wbytes);
            load_lds16(Bg + (long)c * 32 * K + kb, (char*)Bs + c * 4096 + wbytes);
        }
        __syncthreads();   // compiler emits s_waitcnt vmcnt(0) before barrier
#pragma unroll
        for (int s = 0; s < 2; ++s) {
            bf16x8 af[4], bfv[4];
            const int ch = ((s << 2) + qd) ^ (fr & 7);  // un-swizzle (row&7==fr&7)
#pragma unroll
            for (int i = 0; i < 4; ++i)
                af[i] = *(const bf16x8*)(As + (wm + i * 16 + fr) * 64 + ch * 8);
#pragma unroll
            for (int j = 0; j < 4; ++j)
                bfv[j] = *(const bf16x8*)(Bs + (wn + j * 16 + fr) * 64 + ch * 8);
#pragma unroll
            for (int i = 0; i < 4; ++i)
#pragma unroll
                for (int j = 0; j < 4; ++j)
                    acc[i][j] = __builtin_amdgcn_mfma_f32_16x16x32_bf16(
                        af[i], bfv[j], acc[i][j], 0, 0, 0);
        }
    }

    // C/D layout: col = fr, row = qd*4 + reg
    if (MODE == 0) {
        const int which = nt >> 3;  // 0:q 1:k 2:v
        __hip_bfloat16* dst = (which == 0) ? o0 : (which == 1) ? o1 : o2;
        const int colbase = ((nt & 7) << 7) + wn;
        const bool act = (which < 2);
#pragma unroll
        for (int i = 0; i < 4; ++i) {
            const long mrow = m0 + wm + i * 16 + qd * 4;
#pragma unroll
            for (int r = 0; r < 4; ++r) {
                const long moff = (mrow + r) * 1024;
#pragma unroll
                for (int j = 0; j < 4; ++j) {
                    float v = acc[i][j][r];
                    if (act) v = fmaxf(v, 0.f) + 0.125f;
                    dst[moff + colbase + j * 16 + fr] = __float2bfloat16(v);
                }
            }
        }
    } else {
        const long nbase = n0 + wn;
#pragma unroll
        for (int i = 0; i < 4; ++i) {
            const long mrow = m0 + wm + i * 16 + qd * 4;
#pragma unroll
            for (int r = 0; r < 4; ++r) {
                const long moff = (mrow + r) * 1024;
#pragma unroll
                for (int j = 0; j < 4; ++j)
                    outf[moff + nbase + j * 16 + fr] =
                        acc[i][j][r] + bias[nbase + j * 16 + fr];
            }
        }
    }
}

// ---------------------------------------------------------------------------
// Phase 2: kv[bh,e,d] partials over n, 14-way row split x 4-way col split.
// Grid 448 = (bb 8) x (hq 4: 256-col quarter) x (sp 14: 224 rows).
// ~2 blocks/CU -> one block's staging latency hides under the other's FMA
// (R3 post-mortem: 224 blocks = 1 wave/SIMD left the serial chain
//  {global load ~700cy -> LDS cvt/store -> barrier -> 2176cy FMA} exposed).
// 256 thr = 4 heads x (16 e-blk(4) x 4 d-blk(16)); thread tile 4e x 16d.
// kvp written in MFMA-B-FRAGMENT order: linear idx
// ((s2*4+j)*64 + qd*16 + fr)*8 + jj8, e = s2*32+qd*8+jj8, d = j*16+fr.
// Thread e = E*4+jj (E 0..15): s2=E>>3, qd=(E>>1)&3, jj8=(E&1)*4+jj.
// ---------------------------------------------------------------------------
__global__ __launch_bounds__(256)
void kv_partial_kernel(const __hip_bfloat16* __restrict__ kbuf,
                       const __hip_bfloat16* __restrict__ vbuf,
                       float* __restrict__ kvp,    // [14][128][4096] frag-order
                       float* __restrict__ ksump)  // [14][128][64]
{
    __shared__ float kf[8][256];
    __shared__ float vf[8][256];
    const int t   = threadIdx.x;
    const int bid = blockIdx.x;
    const int sp  = bid % 14;
    const int hq  = (bid / 14) & 3;          // 256-col quarter
    const int bb  = bid / 56;
    const long rowstart = (long)bb * 3136 + sp * 224;

    const int hsub = t >> 6;                 // head within quarter (0..3)
    const int w    = t & 63;
    const int E    = w >> 2;                 // e-block 0..15 (4 elems)
    const int Dq   = w & 3;                  // d-block 0..3 (16 elems)
    const int cb   = hsub * 64;
    const int e0   = cb + E * 4;
    const int d0   = cb + Dq * 16;

    float kvacc[4][16];
#pragma unroll
    for (int i = 0; i < 4; ++i)
#pragma unroll
        for (int j = 0; j < 16; ++j) kvacc[i][j] = 0.f;
    float ksacc[4] = {0, 0, 0, 0};

    for (int it = 0; it < 28; ++it) {
        __syncthreads();
#pragma unroll
        for (int i = 0; i < 2; ++i) {
            const int idx = t + (i << 8);            // 0..511
            const int rr  = (idx >> 5) & 7;
            const int c   = idx & 31;
            const long grow = rowstart + it * 8 + rr;
            const __hip_bfloat16* srcp =
                ((idx < 256) ? kbuf : vbuf) + grow * 1024 + hq * 256 + c * 8;
            bf16x8 v8 = *(const bf16x8*)srcp;
            float* dstp = (idx < 256) ? &kf[rr][c * 8] : &vf[rr][c * 8];
#pragma unroll
            for (int jj = 0; jj < 8; ++jj)
                dstp[jj] = bf2f((unsigned short)v8[jj]);
        }
        __syncthreads();
#pragma unroll
        for (int r = 0; r < 8; ++r) {
            float ke[4], vd[16];
#pragma unroll
            for (int i = 0; i < 4; ++i)  ke[i] = kf[r][e0 + i];
#pragma unroll
            for (int j = 0; j < 16; ++j) vd[j] = vf[r][d0 + j];
#pragma unroll
            for (int i = 0; i < 4; ++i) {
                ksacc[i] += ke[i];
#pragma unroll
                for (int j = 0; j < 16; ++j)
                    kvacc[i][j] += ke[i] * vd[j];
            }
        }
    }

    const int bh  = bb * 16 + hq * 4 + hsub;
    const int s2  = E >> 3;
    const int qd  = (E >> 1) & 3;
    const int off = (E & 1) * 4;
    float* outp = kvp + ((long)sp * 128 + bh) * 4096
                      + ((s2 * 4 + Dq) * 64 + qd * 16) * 8 + off;
#pragma unroll
    for (int fr = 0; fr < 16; ++fr)
#pragma unroll
        for (int jj = 0; jj < 4; ++jj)
            outp[fr * 8 + jj] = kvacc[jj][fr];
    if (Dq == 0) {
#pragma unroll
        for (int i = 0; i < 4; ++i)
            ksump[sp * 8192 + bh * 64 + E * 4 + i] = ksacc[i];
    }
}

// ---------------------------------------------------------------------------
// Phase 2b: reduce 14 partials; kv -> bf16 frag-order, ksum -> fp32.
// ---------------------------------------------------------------------------
__global__ __launch_bounds__(256)
void reduce_kv_kernel(const float* __restrict__ kvp, const float* __restrict__ ksump,
                      unsigned short* __restrict__ kvb, float* __restrict__ ksum)
{
    const int idx = blockIdx.x * 256 + threadIdx.x;
    if (idx < 128 * 4096) {
        float a = 0.f;
#pragma unroll
        for (int s = 0; s < 14; ++s) a += kvp[(long)s * 128 * 4096 + idx];
        kvb[idx] = f2bf(a);
    } else {
        const int j = idx - 128 * 4096;
        if (j < 128 * 64) {
            float a = 0.f;
#pragma unroll
            for (int s = 0; s < 14; ++s) a += ksump[s * 8192 + j];
            ksum[j] = a;
        }
    }
}

// ---------------------------------------------------------------------------
// Phase 3: out2 = (q @ kv) * z via MFMA (K=64). Block = 64 rows x 64 d, one h.
// kv read as pre-packed B-fragments (one coalesced dwordx4 per frag).
// qs padded to 72 (144 B row stride, 16B-aligned); z computed by all 4 waves.
// ---------------------------------------------------------------------------
__global__ __launch_bounds__(256)
void attn_out_kernel(const __hip_bfloat16* __restrict__ qbuf,
                     const unsigned short* __restrict__ kvb,  // [128][4096] frag-order
                     const float* __restrict__ ksum,          // [128][64]
                     __hip_bfloat16* __restrict__ out2)
{
    __shared__ __attribute__((aligned(16))) unsigned short qs[64][72];
    __shared__ float kss[64];
    __shared__ float zpart[4][64];
    __shared__ float zs[64];
    const int t   = threadIdx.x;
    const int bid = blockIdx.x;
    const int mc  = bid % 49;
    const int h   = (bid / 49) & 15;
    const int bb  = bid / 784;
    const long bh = bb * 16 + h;
    const long mbase = (long)bb * 3136 + mc * 64;

#pragma unroll
    for (int i = 0; i < 2; ++i) {
        const int idx = t + (i << 8);
        const int row = idx >> 3;
        const int c   = idx & 7;
        *(bf16x8*)&qs[row][c * 8] =
            *(const bf16x8*)(qbuf + (mbase + row) * 1024 + h * 64 + c * 8);
    }
    if (t < 64) kss[t] = ksum[bh * 64 + t];
    __syncthreads();
    {   // z partial dot: wave w covers e in [w*16, w*16+16), rotated per lane
        const int zr_ = t & 63, zp_ = t >> 6;
        float p = 0.f;
#pragma unroll
        for (int ee = 0; ee < 16; ++ee) {
            const int e = zp_ * 16 + ((ee + zr_) & 15);
            p += bf2f(qs[zr_][e]) * kss[e];
        }
        zpart[zp_][zr_] = p;
    }
    __syncthreads();
    if (t < 64)
        zs[t] = 1.f / (zpart[0][t] + zpart[1][t] + zpart[2][t] + zpart[3][t] + 1e-6f);
    __syncthreads();

    const int lane = t & 63;
    const int wv   = t >> 6;
    const int fr   = lane & 15;
    const int qd   = lane >> 4;

    bf16x8 bfv[2][4];
#pragma unroll
    for (int s2 = 0; s2 < 2; ++s2)
#pragma unroll
        for (int j = 0; j < 4; ++j)
            bfv[s2][j] = *(const bf16x8*)(kvb + bh * 4096 + ((s2 * 4 + j) * 64 + lane) * 8);

    const bf16x8 af0 = *(const bf16x8*)&qs[wv * 16 + fr][qd * 8];
    const bf16x8 af1 = *(const bf16x8*)&qs[wv * 16 + fr][32 + qd * 8];

    float zr[4];
#pragma unroll
    for (int r = 0; r < 4; ++r) zr[r] = zs[wv * 16 + qd * 4 + r];

#pragma unroll
    for (int j = 0; j < 4; ++j) {
        f32x4 acc = {};
        acc = __builtin_amdgcn_mfma_f32_16x16x32_bf16(af0, bfv[0][j], acc, 0, 0, 0);
        acc = __builtin_amdgcn_mfma_f32_16x16x32_bf16(af1, bfv[1][j], acc, 0, 0, 0);
#pragma unroll
        for (int r = 0; r < 4; ++r) {
            const long m = mbase + wv * 16 + qd * 4 + r;
            out2[m * 1024 + h * 64 + j * 16 + fr] = __float2bfloat16(acc[r] * zr[r]);
        }
    }
}

// ---------------------------------------------------------------------------
extern "C" void kernel_launch(void* const* d_in, const int* in_sizes, int n_in,
                              void* d_out, int out_size, void* d_ws, size_t ws_size,
                              hipStream_t stream)
{
    const float* x      = (const float*)d_in[0];
    const float* w_qkv  = (const float*)d_in[1];
    const float* w_proj = (const float*)d_in[2];
    const float* b_proj = (const float*)d_in[3];
    float* out = (float*)d_out;

    const long M = 25088;  // 128*196
    char* ws = (char*)d_ws;
    size_t off = 0;
    auto alloc = [&](size_t bytes) {
        char* p = ws + off;
        off += (bytes + 255) & ~(size_t)255;
        return p;
    };
    // ws (~112 MB): xb region reused as kvp/ksump after QKV GEMM consumes xb.
    char* xb_region = alloc(M * 1024 * 2);                 // 51.4 MB
    unsigned short* xb     = (unsigned short*)xb_region;
    float*          kvp    = (float*)xb_region;            // alias: 14*128*4096*4 = 29.4 MB
    float*          ksump  = (float*)(xb_region + (size_t)14 * 128 * 4096 * 4);
    unsigned short* wqkvb  = (unsigned short*)alloc((size_t)3072 * 1024 * 2);
    unsigned short* wprojb = (unsigned short*)alloc((size_t)1024 * 1024 * 2);
    unsigned short* vbuf   = (unsigned short*)alloc(M * 1024 * 2);
    unsigned short* kvb    = (unsigned short*)alloc((size_t)128 * 4096 * 2);
    float*          ksumr  = (float*)alloc((size_t)128 * 64 * 4);
    // d_out (103 MB) hosts qbuf+kbuf (both dead before final GEMM writes it).
    __hip_bfloat16* qbuf = (__hip_bfloat16*)d_out;
    __hip_bfloat16* kbuf = qbuf + M * 1024;
    __hip_bfloat16* out2 = (__hip_bfloat16*)vbuf;  // v dead after phase 2

    // 0) bf16 conversions, single launch (block ranges: 12544 x / 1536 / 512)
    cvt_all_kernel<<<14592, 256, 0, stream>>>(x, xb, w_qkv, wqkvb, w_proj, wprojb);
    // 1) qkv GEMM, fused relu+0.125, scatter q/k/v
    gemm_bt_kernel<0><<<196 * 24, 256, 0, stream>>>(
        xb, wqkvb, qbuf, kbuf, (__hip_bfloat16*)vbuf, nullptr, nullptr);
    // 2) kv/ksum partials (frag-ordered), 448 blocks (~2/CU)
    kv_partial_kernel<<<448, 256, 0, stream>>>(kbuf, (const __hip_bfloat16*)vbuf, kvp, ksump);
    // 2b) reduce -> kvb bf16 + ksum fp32
    reduce_kv_kernel<<<2080, 256, 0, stream>>>(kvp, ksump, kvb, ksumr);
    // 3) out2 = (q @ kv) * z   (MFMA, K=64)
    attn_out_kernel<<<8 * 16 * 49, 256, 0, stream>>>(qbuf, kvb, ksumr, out2);
    // 4) out = out2 @ w_proj^T + bias
    gemm_bt_kernel<1><<<196 * 8, 256, 0, stream>>>(
        (const unsigned short*)out2, wprojb, nullptr, nullptr, nullptr, out, b_proj);
}

// Round 5
// 479.089 us; speedup vs baseline: 1.1705x; 1.0775x over previous
//
#include <hip/hip_runtime.h>
#include <hip/hip_bf16.h>
#include <stdint.h>

typedef __attribute__((ext_vector_type(8))) short bf16x8;   // 8 bf16 = 4 VGPRs
typedef __attribute__((ext_vector_type(4))) float f32x4;

__device__ __forceinline__ unsigned short f2bf(float f) {
    unsigned u = __builtin_bit_cast(unsigned, f);
    u += 0x7FFF + ((u >> 16) & 1);        // RNE (finite inputs)
    return (unsigned short)(u >> 16);
}
__device__ __forceinline__ float bf2f(unsigned short h) {
    return __builtin_bit_cast(float, (unsigned)h << 16);
}
__device__ __forceinline__ void load_lds16(const void* g, void* l) {
    __builtin_amdgcn_global_load_lds(
        (const __attribute__((address_space(1))) void*)g,
        (__attribute__((address_space(3))) void*)l, 16, 0, 0);
}

// ---------------------------------------------------------------------------
// fp32 -> bf16 bulk convert, all three tensors in ONE launch.
// Block ranges: [0,12544) x, [12544,14080) w_qkv, [14080,14592) w_proj.
// Each range's element count divisible by 2048; one thread = 8 elems.
// ---------------------------------------------------------------------------
__global__ __launch_bounds__(256)
void cvt_all_kernel(const float* __restrict__ x,      unsigned short* __restrict__ xb,
                    const float* __restrict__ wqkv,   unsigned short* __restrict__ wqkvb,
                    const float* __restrict__ wproj,  unsigned short* __restrict__ wprojb)
{
    const int bid = blockIdx.x;
    const float* src; unsigned short* dst; long base;
    if (bid < 12544)      { src = x;     dst = xb;     base = bid; }
    else if (bid < 14080) { src = wqkv;  dst = wqkvb;  base = bid - 12544; }
    else                  { src = wproj; dst = wprojb; base = bid - 14080; }
    const long i = (base * 256 + threadIdx.x) * 8;
    const float4 a = *(const float4*)(src + i);
    const float4 b = *(const float4*)(src + i + 4);
    bf16x8 r;
    r[0] = (short)f2bf(a.x); r[1] = (short)f2bf(a.y);
    r[2] = (short)f2bf(a.z); r[3] = (short)f2bf(a.w);
    r[4] = (short)f2bf(b.x); r[5] = (short)f2bf(b.y);
    r[6] = (short)f2bf(b.z); r[7] = (short)f2bf(b.w);
    *(bf16x8*)(dst + i) = r;
}

// ---------------------------------------------------------------------------
// C[m,n] = sum_k A[m,k]*Bt[n,k], K=1024, bf16 operands, K-contiguous.
// 128x128 tile, 4 waves, 64x64/wave, 4x4 x mfma 16x16x32. BK=64.
// Staging: global_load_lds width=16 (m97), XOR chunk-swizzle (chunk^=row&7)
// so frag ds_read_b128 is 2-way (free). Group-swizzled grid for L2 locality.
// XCD-chunk remap (T1): blockIdx round-robins XCDs, so remap bid so each XCD
// owns a CONTIGUOUS run of groups -> group's A-panel (2MB) stays hot in that
// XCD's 4MB L2 and each B-tile is consumed by 8 consecutive same-XCD blocks.
// (R4 counters: FETCH 396MB vs 58MB inputs = 7x over-fetch, cross-XCD B churn.)
// MODE 0: epilogue relu+0.125 on q,k; scatter bf16 q/k/v. MODE 1: +bias, fp32.
// [R1/R2: 256^2 8-phase variants measured slower on this shape — keep 128^2.]
// ---------------------------------------------------------------------------
template<int MODE>
__global__ __launch_bounds__(256, 2)
void gemm_bt_kernel(const unsigned short* __restrict__ A,
                    const unsigned short* __restrict__ Bt,
                    __hip_bfloat16* __restrict__ o0,
                    __hip_bfloat16* __restrict__ o1,
                    __hip_bfloat16* __restrict__ o2,
                    float* __restrict__ outf,
                    const float* __restrict__ bias)
{
    constexpr int K   = 1024;
    constexpr int NT  = (MODE == 0) ? 24 : 8;
    constexpr int NWG = 196 * NT;            // 4704 / 1568, both % 8 == 0
    __shared__ __attribute__((aligned(16))) unsigned short As[128 * 64];
    __shared__ __attribute__((aligned(16))) unsigned short Bs[128 * 64];

    // XCD-chunk remap (bijective: NWG%8==0), then group-major swizzle:
    // 8 m-tiles share B-tiles among consecutively-numbered (= same-XCD) blocks
    const int xcd   = blockIdx.x & 7;
    const int bid   = xcd * (NWG / 8) + (blockIdx.x >> 3);
    const int npg   = 8 * NT;
    const int group = bid / npg;
    const int rem   = bid - group * npg;
    const int gm    = (196 - group * 8 < 8) ? (196 - group * 8) : 8;
    const int mt    = group * 8 + rem % gm;
    const int nt    = rem / gm;
    const long m0 = (long)mt * 128;
    const long n0 = (long)nt * 128;

    const int t    = threadIdx.x;
    const int lane = t & 63;
    const int wv   = t >> 6;
    const int wm   = (wv & 1) << 6;
    const int wn   = (wv >> 1) << 6;
    const int fr   = lane & 15;
    const int qd   = lane >> 4;

    f32x4 acc[4][4] = {};

    // staging: thread t -> LDS row c*32 + (t>>3), LDS chunk t&7, which holds
    // global chunk (t&7)^(row&7). LDS dest = uniform base + lane*16.
    const int srow   = t >> 3;                  // 0..31
    const int gch    = (t & 7) ^ (srow & 7);
    const int wbytes = (t & 192) << 4;          // wave id * 1024

    const unsigned short* Ag = A  + (m0 + srow) * K + gch * 8;
    const unsigned short* Bg = Bt + (n0 + srow) * K + gch * 8;

    for (int kb = 0; kb < K; kb += 64) {
        __syncthreads();
#pragma unroll
        for (int c = 0; c < 4; ++c) {
            load_lds16(Ag + (long)c * 32 * K + kb, (char*)As + c * 4096 + wbytes);
            load_lds16(Bg + (long)c * 32 * K + kb, (char*)Bs + c * 4096 + wbytes);
        }
        __syncthreads();   // compiler emits s_waitcnt vmcnt(0) before barrier
#pragma unroll
        for (int s = 0; s < 2; ++s) {
            bf16x8 af[4], bfv[4];
            const int ch = ((s << 2) + qd) ^ (fr & 7);  // un-swizzle (row&7==fr&7)
#pragma unroll
            for (int i = 0; i < 4; ++i)
                af[i] = *(const bf16x8*)(As + (wm + i * 16 + fr) * 64 + ch * 8);
#pragma unroll
            for (int j = 0; j < 4; ++j)
                bfv[j] = *(const bf16x8*)(Bs + (wn + j * 16 + fr) * 64 + ch * 8);
#pragma unroll
            for (int i = 0; i < 4; ++i)
#pragma unroll
                for (int j = 0; j < 4; ++j)
                    acc[i][j] = __builtin_amdgcn_mfma_f32_16x16x32_bf16(
                        af[i], bfv[j], acc[i][j], 0, 0, 0);
        }
    }

    // C/D layout: col = fr, row = qd*4 + reg
    if (MODE == 0) {
        const int which = nt >> 3;  // 0:q 1:k 2:v
        __hip_bfloat16* dst = (which == 0) ? o0 : (which == 1) ? o1 : o2;
        const int colbase = ((nt & 7) << 7) + wn;
        const bool act = (which < 2);
#pragma unroll
        for (int i = 0; i < 4; ++i) {
            const long mrow = m0 + wm + i * 16 + qd * 4;
#pragma unroll
            for (int r = 0; r < 4; ++r) {
                const long moff = (mrow + r) * 1024;
#pragma unroll
                for (int j = 0; j < 4; ++j) {
                    float v = acc[i][j][r];
                    if (act) v = fmaxf(v, 0.f) + 0.125f;
                    dst[moff + colbase + j * 16 + fr] = __float2bfloat16(v);
                }
            }
        }
    } else {
        const long nbase = n0 + wn;
#pragma unroll
        for (int i = 0; i < 4; ++i) {
            const long mrow = m0 + wm + i * 16 + qd * 4;
#pragma unroll
            for (int r = 0; r < 4; ++r) {
                const long moff = (mrow + r) * 1024;
#pragma unroll
                for (int j = 0; j < 4; ++j)
                    outf[moff + nbase + j * 16 + fr] =
                        acc[i][j][r] + bias[nbase + j * 16 + fr];
            }
        }
    }
}

// ---------------------------------------------------------------------------
// Phase 2: kv[bh,e,d] partials over n, 14-way row split x 4-way col split.
// Grid 448 = (bb 8) x (hq 4: 256-col quarter) x (sp 14: 224 rows).
// ~2 blocks/CU -> one block's staging latency hides under the other's FMA.
// 256 thr = 4 heads x (16 e-blk(4) x 4 d-blk(16)); thread tile 4e x 16d.
// kvp written in MFMA-B-FRAGMENT order: linear idx
// ((s2*4+j)*64 + qd*16 + fr)*8 + jj8, e = s2*32+qd*8+jj8, d = j*16+fr.
// Thread e = E*4+jj (E 0..15): s2=E>>3, qd=(E>>1)&3, jj8=(E&1)*4+jj.
// ---------------------------------------------------------------------------
__global__ __launch_bounds__(256)
void kv_partial_kernel(const __hip_bfloat16* __restrict__ kbuf,
                       const __hip_bfloat16* __restrict__ vbuf,
                       float* __restrict__ kvp,    // [14][128][4096] frag-order
                       float* __restrict__ ksump)  // [14][128][64]
{
    __shared__ float kf[8][256];
    __shared__ float vf[8][256];
    const int t   = threadIdx.x;
    const int bid = blockIdx.x;
    const int sp  = bid % 14;
    const int hq  = (bid / 14) & 3;          // 256-col quarter
    const int bb  = bid / 56;
    const long rowstart = (long)bb * 3136 + sp * 224;

    const int hsub = t >> 6;                 // head within quarter (0..3)
    const int w    = t & 63;
    const int E    = w >> 2;                 // e-block 0..15 (4 elems)
    const int Dq   = w & 3;                  // d-block 0..3 (16 elems)
    const int cb   = hsub * 64;
    const int e0   = cb + E * 4;
    const int d0   = cb + Dq * 16;

    float kvacc[4][16];
#pragma unroll
    for (int i = 0; i < 4; ++i)
#pragma unroll
        for (int j = 0; j < 16; ++j) kvacc[i][j] = 0.f;
    float ksacc[4] = {0, 0, 0, 0};

    for (int it = 0; it < 28; ++it) {
        __syncthreads();
#pragma unroll
        for (int i = 0; i < 2; ++i) {
            const int idx = t + (i << 8);            // 0..511
            const int rr  = (idx >> 5) & 7;
            const int c   = idx & 31;
            const long grow = rowstart + it * 8 + rr;
            const __hip_bfloat16* srcp =
                ((idx < 256) ? kbuf : vbuf) + grow * 1024 + hq * 256 + c * 8;
            bf16x8 v8 = *(const bf16x8*)srcp;
            float* dstp = (idx < 256) ? &kf[rr][c * 8] : &vf[rr][c * 8];
#pragma unroll
            for (int jj = 0; jj < 8; ++jj)
                dstp[jj] = bf2f((unsigned short)v8[jj]);
        }
        __syncthreads();
#pragma unroll
        for (int r = 0; r < 8; ++r) {
            float ke[4], vd[16];
#pragma unroll
            for (int i = 0; i < 4; ++i)  ke[i] = kf[r][e0 + i];
#pragma unroll
            for (int j = 0; j < 16; ++j) vd[j] = vf[r][d0 + j];
#pragma unroll
            for (int i = 0; i < 4; ++i) {
                ksacc[i] += ke[i];
#pragma unroll
                for (int j = 0; j < 16; ++j)
                    kvacc[i][j] += ke[i] * vd[j];
            }
        }
    }

    const int bh  = bb * 16 + hq * 4 + hsub;
    const int s2  = E >> 3;
    const int qd  = (E >> 1) & 3;
    const int off = (E & 1) * 4;
    float* outp = kvp + ((long)sp * 128 + bh) * 4096
                      + ((s2 * 4 + Dq) * 64 + qd * 16) * 8 + off;
#pragma unroll
    for (int fr = 0; fr < 16; ++fr)
#pragma unroll
        for (int jj = 0; jj < 4; ++jj)
            outp[fr * 8 + jj] = kvacc[jj][fr];
    if (Dq == 0) {
#pragma unroll
        for (int i = 0; i < 4; ++i)
            ksump[sp * 8192 + bh * 64 + E * 4 + i] = ksacc[i];
    }
}

// ---------------------------------------------------------------------------
// Phase 2b: reduce 14 partials; kv -> bf16 frag-order, ksum -> fp32.
// ---------------------------------------------------------------------------
__global__ __launch_bounds__(256)
void reduce_kv_kernel(const float* __restrict__ kvp, const float* __restrict__ ksump,
                      unsigned short* __restrict__ kvb, float* __restrict__ ksum)
{
    const int idx = blockIdx.x * 256 + threadIdx.x;
    if (idx < 128 * 4096) {
        float a = 0.f;
#pragma unroll
        for (int s = 0; s < 14; ++s) a += kvp[(long)s * 128 * 4096 + idx];
        kvb[idx] = f2bf(a);
    } else {
        const int j = idx - 128 * 4096;
        if (j < 128 * 64) {
            float a = 0.f;
#pragma unroll
            for (int s = 0; s < 14; ++s) a += ksump[s * 8192 + j];
            ksum[j] = a;
        }
    }
}

// ---------------------------------------------------------------------------
// Phase 3: out2 = (q @ kv) * z via MFMA (K=64). Block = 64 rows x 64 d, one h.
// kv read as pre-packed B-fragments (one coalesced dwordx4 per frag).
// qs padded to 72 (144 B row stride, 16B-aligned); z computed by all 4 waves.
// ---------------------------------------------------------------------------
__global__ __launch_bounds__(256)
void attn_out_kernel(const __hip_bfloat16* __restrict__ qbuf,
                     const unsigned short* __restrict__ kvb,  // [128][4096] frag-order
                     const float* __restrict__ ksum,          // [128][64]
                     __hip_bfloat16* __restrict__ out2)
{
    __shared__ __attribute__((aligned(16))) unsigned short qs[64][72];
    __shared__ float kss[64];
    __shared__ float zpart[4][64];
    __shared__ float zs[64];
    const int t   = threadIdx.x;
    const int bid = blockIdx.x;
    const int mc  = bid % 49;
    const int h   = (bid / 49) & 15;
    const int bb  = bid / 784;
    const long bh = bb * 16 + h;
    const long mbase = (long)bb * 3136 + mc * 64;

#pragma unroll
    for (int i = 0; i < 2; ++i) {
        const int idx = t + (i << 8);
        const int row = idx >> 3;
        const int c   = idx & 7;
        *(bf16x8*)&qs[row][c * 8] =
            *(const bf16x8*)(qbuf + (mbase + row) * 1024 + h * 64 + c * 8);
    }
    if (t < 64) kss[t] = ksum[bh * 64 + t];
    __syncthreads();
    {   // z partial dot: wave w covers e in [w*16, w*16+16), rotated per lane
        const int zr_ = t & 63, zp_ = t >> 6;
        float p = 0.f;
#pragma unroll
        for (int ee = 0; ee < 16; ++ee) {
            const int e = zp_ * 16 + ((ee + zr_) & 15);
            p += bf2f(qs[zr_][e]) * kss[e];
        }
        zpart[zp_][zr_] = p;
    }
    __syncthreads();
    if (t < 64)
        zs[t] = 1.f / (zpart[0][t] + zpart[1][t] + zpart[2][t] + zpart[3][t] + 1e-6f);
    __syncthreads();

    const int lane = t & 63;
    const int wv   = t >> 6;
    const int fr   = lane & 15;
    const int qd   = lane >> 4;

    bf16x8 bfv[2][4];
#pragma unroll
    for (int s2 = 0; s2 < 2; ++s2)
#pragma unroll
        for (int j = 0; j < 4; ++j)
            bfv[s2][j] = *(const bf16x8*)(kvb + bh * 4096 + ((s2 * 4 + j) * 64 + lane) * 8);

    const bf16x8 af0 = *(const bf16x8*)&qs[wv * 16 + fr][qd * 8];
    const bf16x8 af1 = *(const bf16x8*)&qs[wv * 16 + fr][32 + qd * 8];

    float zr[4];
#pragma unroll
    for (int r = 0; r < 4; ++r) zr[r] = zs[wv * 16 + qd * 4 + r];

#pragma unroll
    for (int j = 0; j < 4; ++j) {
        f32x4 acc = {};
        acc = __builtin_amdgcn_mfma_f32_16x16x32_bf16(af0, bfv[0][j], acc, 0, 0, 0);
        acc = __builtin_amdgcn_mfma_f32_16x16x32_bf16(af1, bfv[1][j], acc, 0, 0, 0);
#pragma unroll
        for (int r = 0; r < 4; ++r) {
            const long m = mbase + wv * 16 + qd * 4 + r;
            out2[m * 1024 + h * 64 + j * 16 + fr] = __float2bfloat16(acc[r] * zr[r]);
        }
    }
}

// ---------------------------------------------------------------------------
extern "C" void kernel_launch(void* const* d_in, const int* in_sizes, int n_in,
                              void* d_out, int out_size, void* d_ws, size_t ws_size,
                              hipStream_t stream)
{
    const float* x      = (const float*)d_in[0];
    const float* w_qkv  = (const float*)d_in[1];
    const float* w_proj = (const float*)d_in[2];
    const float* b_proj = (const float*)d_in[3];
    float* out = (float*)d_out;

    const long M = 25088;  // 128*196
    char* ws = (char*)d_ws;
    size_t off = 0;
    auto alloc = [&](size_t bytes) {
        char* p = ws + off;
        off += (bytes + 255) & ~(size_t)255;
        return p;
    };
    // ws (~112 MB): xb region reused as kvp/ksump after QKV GEMM consumes xb.
    char* xb_region = alloc(M * 1024 * 2);                 // 51.4 MB
    unsigned short* xb     = (unsigned short*)xb_region;
    float*          kvp    = (float*)xb_region;            // alias: 14*128*4096*4 = 29.4 MB
    float*          ksump  = (float*)(xb_region + (size_t)14 * 128 * 4096 * 4);
    unsigned short* wqkvb  = (unsigned short*)alloc((size_t)3072 * 1024 * 2);
    unsigned short* wprojb = (unsigned short*)alloc((size_t)1024 * 1024 * 2);
    unsigned short* vbuf   = (unsigned short*)alloc(M * 1024 * 2);
    unsigned short* kvb    = (unsigned short*)alloc((size_t)128 * 4096 * 2);
    float*          ksumr  = (float*)alloc((size_t)128 * 64 * 4);
    // d_out (103 MB) hosts qbuf+kbuf (both dead before final GEMM writes it).
    __hip_bfloat16* qbuf = (__hip_bfloat16*)d_out;
    __hip_bfloat16* kbuf = qbuf + M * 1024;
    __hip_bfloat16* out2 = (__hip_bfloat16*)vbuf;  // v dead after phase 2

    // 0) bf16 conversions, single launch (block ranges: 12544 x / 1536 / 512)
    cvt_all_kernel<<<14592, 256, 0, stream>>>(x, xb, w_qkv, wqkvb, w_proj, wprojb);
    // 1) qkv GEMM (XCD-chunked), fused relu+0.125, scatter q/k/v
    gemm_bt_kernel<0><<<196 * 24, 256, 0, stream>>>(
        xb, wqkvb, qbuf, kbuf, (__hip_bfloat16*)vbuf, nullptr, nullptr);
    // 2) kv/ksum partials (frag-ordered), 448 blocks (~2/CU)
    kv_partial_kernel<<<448, 256, 0, stream>>>(kbuf, (const __hip_bfloat16*)vbuf, kvp, ksump);
    // 2b) reduce -> kvb bf16 + ksum fp32
    reduce_kv_kernel<<<2080, 256, 0, stream>>>(kvp, ksump, kvb, ksumr);
    // 3) out2 = (q @ kv) * z   (MFMA, K=64)
    attn_out_kernel<<<8 * 16 * 49, 256, 0, stream>>>(qbuf, kvb, ksumr, out2);
    // 4) out = out2 @ w_proj^T + bias (XCD-chunked)
    gemm_bt_kernel<1><<<196 * 8, 256, 0, stream>>>(
        (const unsigned short*)out2, wprojb, nullptr, nullptr, nullptr, out, b_proj);
}